// Round 18
// baseline (64.535 us; speedup 1.0000x reference)
//
#include <hip/hip_runtime.h>

#define T_SEQ 4096
#define C_DIM 1024
#define HD 64
#define NCH 272           // chunks per batch: q-tile=128, chunk=4 kv-tiles

typedef __attribute__((ext_vector_type(8))) __bf16 bf16x8;
typedef __attribute__((ext_vector_type(8))) unsigned short us8;
typedef __attribute__((ext_vector_type(4))) unsigned short us4;
typedef __attribute__((ext_vector_type(4))) float f32x4;
typedef __attribute__((ext_vector_type(16))) float f32x16;

// 0.125 (1/sqrt(64)) * log2(e): fold softmax scale + base-2 conversion into q
#define QSCALE 0.18033688011112042f

__device__ __forceinline__ unsigned short f2bf(float f) {
    union { float f; unsigned u; } x; x.f = f;
    unsigned r = x.u + 0x7FFFu + ((x.u >> 16) & 1u);   // RNE
    return (unsigned short)(r >> 16);
}

__device__ __forceinline__ float bf2f(unsigned short u) {
    union { unsigned u; float f; } x; x.u = ((unsigned)u) << 16;
    return x.f;
}

__device__ __forceinline__ us8 cvt8(float4 a, float4 b) {
    union { __bf16 h[8]; us8 v; } u;
    u.h[0] = (__bf16)a.x; u.h[1] = (__bf16)a.y; u.h[2] = (__bf16)a.z; u.h[3] = (__bf16)a.w;
    u.h[4] = (__bf16)b.x; u.h[5] = (__bf16)b.y; u.h[6] = (__bf16)b.z; u.h[7] = (__bf16)b.w;
    return u.v;
}

__device__ __forceinline__ us4 cvt4f(float a, float b, float c, float d) {
    union { __bf16 h[4]; us4 v; } u;
    u.h[0] = (__bf16)a; u.h[1] = (__bf16)b; u.h[2] = (__bf16)c; u.h[3] = (__bf16)d;
    return u.v;
}

__device__ __forceinline__ f32x16 zero16() {
    f32x16 v;
    #pragma unroll
    for (int j = 0; j < 16; ++j) v[j] = 0.f;
    return v;
}

// XOR-swizzle on a short-index with 64-short (128 B) rows. Both write & read.
__device__ __forceinline__ int swzs(int idx) {
    return idx ^ ((((idx) >> 6) & 7) << 3);
}

// chunk-offset of q-tile qt (chunks of 4 kv-tiles; tile qt has 2qt+2 kv-tiles)
__device__ __forceinline__ int offf(int qt) {
    const int m = qt >> 1;
    return (qt & 1) ? (m + 1) * (m + 1) : m * m + m;
}

// ---------------- K0: W[1024][64] f32 -> wt2[16][192][64] bf16 --------------
// k-chunked layout: each K-step's W slice is a contiguous 24 KB block.
__global__ __launch_bounds__(256) void k_wtrans(const float* __restrict__ Wq,
                                                const float* __restrict__ Wk,
                                                const float* __restrict__ Wv,
                                                unsigned short* __restrict__ wt_g) {
    __shared__ unsigned short tile[64][72];
    const int bx = blockIdx.x;
    const int which = bx >> 4;          // 0..2
    const int kc = bx & 15;             // k-chunk
    const int k0 = kc * 64;
    const float* W = (which == 0) ? Wq : ((which == 1) ? Wk : Wv);
    const int t = threadIdx.x;
    {
        const int r = t >> 2, c0 = (t & 3) * 16;
        const float4* src = reinterpret_cast<const float4*>(W + (k0 + r) * HD + c0);
        #pragma unroll
        for (int i = 0; i < 4; ++i) {
            float4 v = src[i];
            tile[r][c0 + 4 * i + 0] = f2bf(v.x);
            tile[r][c0 + 4 * i + 1] = f2bf(v.y);
            tile[r][c0 + 4 * i + 2] = f2bf(v.z);
            tile[r][c0 + 4 * i + 3] = f2bf(v.w);
        }
    }
    __syncthreads();
    {
        const int n = t >> 2, kc0 = (t & 3) * 16;
        alignas(16) unsigned short o[16];
        #pragma unroll
        for (int i = 0; i < 16; ++i) o[i] = tile[kc0 + i][n];
        unsigned short* dst = wt_g + (size_t)kc * 12288 + (which * 64 + n) * 64 + kc0;
        *reinterpret_cast<us8*>(dst)     = *reinterpret_cast<const us8*>(&o[0]);
        *reinterpret_cast<us8*>(dst + 8) = *reinterpret_cast<const us8*>(&o[8]);
    }
}

// ---------------- K1: q,k,v projections, BM=32, W staged via LDS ------------
// (R12 best form.) Per K-step: cooperative COALESCED load of the 24 KB W
// chunk (6x16B/thread) + 32x64 x tile into dbuf LDS; 12 MFMA/wave; 1 barrier.
__global__ __launch_bounds__(256) void k_proj(const float* __restrict__ x,
                                              const unsigned short* __restrict__ wt_g,
                                              unsigned short* __restrict__ qs,
                                              unsigned short* __restrict__ ksb,
                                              unsigned short* __restrict__ vt) {
    // shorts: xs dbuf 2*2304 @0, W dbuf 2*13824 @4608 (64.5 KB -> 2 blocks/CU)
    __shared__ unsigned short smem[32256];
    const int tid = threadIdx.x;
    const int w = tid >> 6, lane = tid & 63;
    const int l15 = lane & 15, g = lane >> 4;
    const int m0 = blockIdx.x * 32;
    const int sr = tid >> 3, sc0 = (tid & 7) * 8;
    const float* xrow = x + (size_t)(m0 + sr) * C_DIM + sc0;

    f32x4 acc[3][2];
    #pragma unroll
    for (int mf = 0; mf < 3; ++mf)
        #pragma unroll
        for (int nf = 0; nf < 2; ++nf)
            acc[mf][nf] = (f32x4){0.f, 0.f, 0.f, 0.f};

    // prologue: stage step 0 into buf 0
    {
        float4 xa = *reinterpret_cast<const float4*>(xrow);
        float4 xb = *reinterpret_cast<const float4*>(xrow + 4);
        *reinterpret_cast<us8*>(smem + sr * 72 + sc0) = cvt8(xa, xb);
        #pragma unroll
        for (int j = 0; j < 6; ++j) {
            const int li = tid + 256 * j;
            us8 v = *reinterpret_cast<const us8*>(wt_g + li * 8);
            *reinterpret_cast<us8*>(smem + 4608 + (li >> 3) * 72 + (li & 7) * 8) = v;
        }
    }
    __syncthreads();

    for (int kk = 0; kk < 16; ++kk) {
        const int cur = kk & 1;
        const bool pf = (kk < 15);
        const int xb = cur * 2304;
        const int wb = 4608 + cur * 13824;
        const int xbn = (cur ^ 1) * 2304;
        const int wbn = 4608 + (cur ^ 1) * 13824;
        float4 na, nb;
        us8 wn[6];
        if (pf) {   // issue step kk+1 loads (coalesced; hidden under MFMA)
            na = *reinterpret_cast<const float4*>(xrow + (kk + 1) * 64);
            nb = *reinterpret_cast<const float4*>(xrow + (kk + 1) * 64 + 4);
            const unsigned short* wsrc = wt_g + (size_t)(kk + 1) * 12288;
            #pragma unroll
            for (int j = 0; j < 6; ++j)
                wn[j] = *reinterpret_cast<const us8*>(wsrc + (tid + 256 * j) * 8);
        }
        #pragma unroll
        for (int k2 = 0; k2 < 2; ++k2) {
            bf16x8 bfr[2];
            #pragma unroll
            for (int nf = 0; nf < 2; ++nf)
                bfr[nf] = *reinterpret_cast<const bf16x8*>(
                    smem + xb + (nf * 16 + l15) * 72 + k2 * 32 + g * 8);
            #pragma unroll
            for (int mf = 0; mf < 3; ++mf) {
                bf16x8 afr = *reinterpret_cast<const bf16x8*>(
                    smem + wb + ((3 * w + mf) * 16 + l15) * 72 + k2 * 32 + g * 8);
                #pragma unroll
                for (int nf = 0; nf < 2; ++nf)
                    acc[mf][nf] = __builtin_amdgcn_mfma_f32_16x16x32_bf16(
                        afr, bfr[nf], acc[mf][nf], 0, 0, 0);
            }
        }
        if (pf) {   // write step kk+1 into the other buffers
            *reinterpret_cast<us8*>(smem + xbn + sr * 72 + sc0) = cvt8(na, nb);
            #pragma unroll
            for (int j = 0; j < 6; ++j) {
                const int li = tid + 256 * j;
                *reinterpret_cast<us8*>(smem + wbn + (li >> 3) * 72 + (li & 7) * 8) = wn[j];
            }
        }
        __syncthreads();
    }

    // epilogue: C^T frags -> out_lds[32 m][208 n] bf16 (reuses smem)
    unsigned short* out_lds = smem;
    #pragma unroll
    for (int mf = 0; mf < 3; ++mf) {
        const int Mfr = 3 * w + mf;                    // n = 16*Mfr..
        const float s = (Mfr < 4) ? QSCALE : 1.0f;     // scale q columns (n<64)
        #pragma unroll
        for (int nf = 0; nf < 2; ++nf) {
            union { __bf16 h[4]; us4 v; } u;
            #pragma unroll
            for (int r = 0; r < 4; ++r) u.h[r] = (__bf16)(acc[mf][nf][r] * s);
            *reinterpret_cast<us4*>(out_lds + (nf * 16 + l15) * 208 + Mfr * 16 + 4 * g) = u.v;
        }
    }
    __syncthreads();
    {
        const int r = tid >> 3, c = (tid & 7) * 8;
        const size_t gm = (size_t)(m0 + r);
        *reinterpret_cast<us8*>(qs + gm * 64 + c)  = *reinterpret_cast<const us8*>(out_lds + r * 208 + c);
        *reinterpret_cast<us8*>(ksb + gm * 64 + c) = *reinterpret_cast<const us8*>(out_lds + r * 208 + 64 + c);
    }
    {
        const int d = tid >> 2, j0 = (tid & 3) * 8;
        const int b = m0 >> 12, t0 = m0 & 4095;
        alignas(16) unsigned short tmp[8];
        #pragma unroll
        for (int j = 0; j < 8; ++j) tmp[j] = out_lds[(j0 + j) * 208 + 128 + d];
        *reinterpret_cast<us8*>(vt + (size_t)(b * 64 + d) * T_SEQ + t0 + j0) =
            *reinterpret_cast<const us8*>(tmp);
    }
}

// ---------------- K2: flash attention, pipelined QK (dual-chain) ------------
// grid (272, 4). Swapped QK^T with mfma_32x32x16; in-register P. NEW: both
// ksub QK chains issue back-to-back (independent -> MFMA pipe stays fed),
// then softmax0+PV0, softmax1+PV1 (P1's VALU overlaps PV0's MFMA latency).
__global__ __launch_bounds__(256) void k_attn(const unsigned short* __restrict__ qs,
                                              const unsigned short* __restrict__ ks,
                                              const unsigned short* __restrict__ vt,
                                              unsigned short* __restrict__ Opart,
                                              float* __restrict__ lw,
                                              float* __restrict__ out) {
    // shorts: kbuf[2][4096] @0, vbuf[2][4096] @8192  (32 KB total)
    __shared__ unsigned short sm[16384];
    const int tid = threadIdx.x;
    const int w = tid >> 6, lane = tid & 63;
    const int l31 = lane & 31, hi = lane >> 5;
    const int batch = blockIdx.y;
    const int i = (NCH - 1) - blockIdx.x;   // big q-tiles dispatched first
    // decode i -> (qt, split s)
    int qt = min(31, (int)(2.0f * sqrtf((float)i)));
    while (offf(qt + 1) <= i) ++qt;
    while (offf(qt) > i) --qt;
    const int s = i - offf(qt);
    const int ns = (qt + 2) >> 1;           // chunks for this q-tile
    const int it0 = s * 4;
    const int it1 = min(it0 + 4, 2 * qt + 2);
    const int qi = qt * 128 + 32 * w + l31;
    const size_t qrow = (size_t)batch * T_SEQ + qi;

    // Q B-frags: slot (hi,j) -> d = df*16 + hi*8 + j (same map as K A-frags)
    bf16x8 qf[4];
    #pragma unroll
    for (int df = 0; df < 4; ++df)
        qf[df] = *reinterpret_cast<const bf16x8*>(qs + qrow * 64 + df * 16 + hi * 8);

    f32x16 accO0 = zero16(), accO1 = zero16();
    float lp0 = 0.f, lp1 = 0.f, lp2 = 0.f, lp3 = 0.f;

    const int sr = tid >> 2, sc0 = (tid & 3) * 16;
    const unsigned short* kbase = ks + ((size_t)batch * T_SEQ + sr) * 64 + sc0;
    const unsigned short* vbase = vt + ((size_t)batch * 64 + sr) * T_SEQ + sc0;

    // V staging permutation: dest[0..15] = src[0..3, 8..11, 4..7, 12..15]
    // so a b128 read at hi*8 yields slots matching k = 4hi + (j&3) + 8*(j>>2).
    {
        us8 a0 = *reinterpret_cast<const us8*>(kbase + (size_t)it0 * 4096);
        us8 a1 = *reinterpret_cast<const us8*>(kbase + (size_t)it0 * 4096 + 8);
        us8 b0 = *reinterpret_cast<const us8*>(vbase + it0 * 64);
        us8 b1 = *reinterpret_cast<const us8*>(vbase + it0 * 64 + 8);
        us8 w0, w1;
        #pragma unroll
        for (int j = 0; j < 4; ++j) { w0[j] = b0[j]; w0[4 + j] = b1[j]; w1[j] = b0[4 + j]; w1[4 + j] = b1[4 + j]; }
        const int kd = sr * 64 + sc0, vd = 8192 + sr * 64 + sc0;
        *reinterpret_cast<us8*>(sm + swzs(kd))     = a0;
        *reinterpret_cast<us8*>(sm + swzs(kd + 8)) = a1;
        *reinterpret_cast<us8*>(sm + swzs(vd))     = w0;
        *reinterpret_cast<us8*>(sm + swzs(vd + 8)) = w1;
    }
    __syncthreads();

    for (int it = it0; it < it1; ++it) {
        const int cur = (it - it0) & 1;
        const bool pf = (it + 1 < it1);
        us8 n0, n1, m0, m1;
        if (pf) {   // issue next tile's loads early (hidden under compute)
            n0 = *reinterpret_cast<const us8*>(kbase + (size_t)(it + 1) * 4096);
            n1 = *reinterpret_cast<const us8*>(kbase + (size_t)(it + 1) * 4096 + 8);
            m0 = *reinterpret_cast<const us8*>(vbase + (it + 1) * 64);
            m1 = *reinterpret_cast<const us8*>(vbase + (it + 1) * 64 + 8);
        }
        const int kb = cur * 4096;
        const int vb = 8192 + cur * 4096;
        const bool diag = (it >= 2 * qt);

        // ---- QK^T for BOTH 32-k sub-tiles: two independent MFMA chains ----
        f32x16 sv0 = zero16(), sv1 = zero16();
        __builtin_amdgcn_s_setprio(1);
        #pragma unroll
        for (int df = 0; df < 4; ++df) {
            bf16x8 a0 = *reinterpret_cast<const bf16x8*>(
                sm + swzs(kb + l31 * 64 + df * 16 + hi * 8));
            bf16x8 a1 = *reinterpret_cast<const bf16x8*>(
                sm + swzs(kb + (32 + l31) * 64 + df * 16 + hi * 8));
            sv0 = __builtin_amdgcn_mfma_f32_32x32x16_bf16(a0, qf[df], sv0, 0, 0, 0);
            sv1 = __builtin_amdgcn_mfma_f32_32x32x16_bf16(a1, qf[df], sv1, 0, 0, 0);
        }
        __builtin_amdgcn_s_setprio(0);
        if (diag) {   // causal mask: k = it*64 + ksub*32 + (rr&3)+8*(rr>>2)+4*hi
            #pragma unroll
            for (int rr = 0; rr < 16; ++rr) {
                const int kidx = it * 64 + (rr & 3) + 8 * (rr >> 2) + 4 * hi;
                if (kidx > qi)      sv0[rr] = -1e30f;
                if (kidx + 32 > qi) sv1[rr] = -1e30f;
            }
        }
        // ---- softmax0 + PV0 ----
        {
            f32x16 pv;
            #pragma unroll
            for (int rr = 0; rr < 16; ++rr) pv[rr] = exp2f(sv0[rr]);
            #pragma unroll
            for (int rr = 0; rr < 4; ++rr) {
                lp0 += pv[4 * rr + 0]; lp1 += pv[4 * rr + 1];
                lp2 += pv[4 * rr + 2]; lp3 += pv[4 * rr + 3];
            }
            us8 bfr0, bfr1;
            {
                us4 c0 = cvt4f(pv[0], pv[1], pv[2], pv[3]);
                us4 c1 = cvt4f(pv[4], pv[5], pv[6], pv[7]);
                us4 c2 = cvt4f(pv[8], pv[9], pv[10], pv[11]);
                us4 c3 = cvt4f(pv[12], pv[13], pv[14], pv[15]);
                #pragma unroll
                for (int j = 0; j < 4; ++j) {
                    bfr0[j] = c0[j]; bfr0[4 + j] = c1[j];
                    bfr1[j] = c2[j]; bfr1[4 + j] = c3[j];
                }
            }
            __builtin_amdgcn_s_setprio(1);
            bf16x8 a00 = *reinterpret_cast<const bf16x8*>(sm + swzs(vb + l31 * 64 + hi * 8));
            bf16x8 a01 = *reinterpret_cast<const bf16x8*>(sm + swzs(vb + l31 * 64 + 16 + hi * 8));
            accO0 = __builtin_amdgcn_mfma_f32_32x32x16_bf16(a00, *reinterpret_cast<bf16x8*>(&bfr0), accO0, 0, 0, 0);
            accO0 = __builtin_amdgcn_mfma_f32_32x32x16_bf16(a01, *reinterpret_cast<bf16x8*>(&bfr1), accO0, 0, 0, 0);
            bf16x8 a10 = *reinterpret_cast<const bf16x8*>(sm + swzs(vb + (32 + l31) * 64 + hi * 8));
            bf16x8 a11 = *reinterpret_cast<const bf16x8*>(sm + swzs(vb + (32 + l31) * 64 + 16 + hi * 8));
            accO1 = __builtin_amdgcn_mfma_f32_32x32x16_bf16(a10, *reinterpret_cast<bf16x8*>(&bfr0), accO1, 0, 0, 0);
            accO1 = __builtin_amdgcn_mfma_f32_32x32x16_bf16(a11, *reinterpret_cast<bf16x8*>(&bfr1), accO1, 0, 0, 0);
            __builtin_amdgcn_s_setprio(0);
        }
        // ---- softmax1 + PV1 (VALU here overlaps PV0's in-flight MFMAs) ----
        {
            f32x16 pv;
            #pragma unroll
            for (int rr = 0; rr < 16; ++rr) pv[rr] = exp2f(sv1[rr]);
            #pragma unroll
            for (int rr = 0; rr < 4; ++rr) {
                lp0 += pv[4 * rr + 0]; lp1 += pv[4 * rr + 1];
                lp2 += pv[4 * rr + 2]; lp3 += pv[4 * rr + 3];
            }
            us8 bfr0, bfr1;
            {
                us4 c0 = cvt4f(pv[0], pv[1], pv[2], pv[3]);
                us4 c1 = cvt4f(pv[4], pv[5], pv[6], pv[7]);
                us4 c2 = cvt4f(pv[8], pv[9], pv[10], pv[11]);
                us4 c3 = cvt4f(pv[12], pv[13], pv[14], pv[15]);
                #pragma unroll
                for (int j = 0; j < 4; ++j) {
                    bfr0[j] = c0[j]; bfr0[4 + j] = c1[j];
                    bfr1[j] = c2[j]; bfr1[4 + j] = c3[j];
                }
            }
            __builtin_amdgcn_s_setprio(1);
            bf16x8 a00 = *reinterpret_cast<const bf16x8*>(sm + swzs(vb + l31 * 64 + 32 + hi * 8));
            bf16x8 a01 = *reinterpret_cast<const bf16x8*>(sm + swzs(vb + l31 * 64 + 48 + hi * 8));
            accO0 = __builtin_amdgcn_mfma_f32_32x32x16_bf16(a00, *reinterpret_cast<bf16x8*>(&bfr0), accO0, 0, 0, 0);
            accO0 = __builtin_amdgcn_mfma_f32_32x32x16_bf16(a01, *reinterpret_cast<bf16x8*>(&bfr1), accO0, 0, 0, 0);
            bf16x8 a10 = *reinterpret_cast<const bf16x8*>(sm + swzs(vb + (32 + l31) * 64 + 32 + hi * 8));
            bf16x8 a11 = *reinterpret_cast<const bf16x8*>(sm + swzs(vb + (32 + l31) * 64 + 48 + hi * 8));
            accO1 = __builtin_amdgcn_mfma_f32_32x32x16_bf16(a10, *reinterpret_cast<bf16x8*>(&bfr0), accO1, 0, 0, 0);
            accO1 = __builtin_amdgcn_mfma_f32_32x32x16_bf16(a11, *reinterpret_cast<bf16x8*>(&bfr1), accO1, 0, 0, 0);
            __builtin_amdgcn_s_setprio(0);
        }
        if (pf) {   // stage next tile into the other buffer (swizzled + V perm)
            us8 w0, w1;
            #pragma unroll
            for (int j = 0; j < 4; ++j) { w0[j] = m0[j]; w0[4 + j] = m1[j]; w1[j] = m0[4 + j]; w1[4 + j] = m1[4 + j]; }
            const int kd = (cur ^ 1) * 4096 + sr * 64 + sc0;
            const int vd = 8192 + (cur ^ 1) * 4096 + sr * 64 + sc0;
            *reinterpret_cast<us8*>(sm + swzs(kd))     = n0;
            *reinterpret_cast<us8*>(sm + swzs(kd + 8)) = n1;
            *reinterpret_cast<us8*>(sm + swzs(vd))     = w0;
            *reinterpret_cast<us8*>(sm + swzs(vd + 8)) = w1;
        }
        __syncthreads();
    }

    // merge partials + cross-half reduce (lane pair (l31,0)/(l31,1) = same q)
    float l_run = (lp0 + lp1) + (lp2 + lp3);
    l_run += __shfl_xor(l_run, 32, 64);

    if (ns == 1) {
        const float inv = 1.0f / l_run;
        #pragma unroll
        for (int rg = 0; rg < 4; ++rg) {
            const int d0 = 4 * hi + 8 * rg;
            f32x4 o0 = {accO0[4 * rg] * inv, accO0[4 * rg + 1] * inv,
                        accO0[4 * rg + 2] * inv, accO0[4 * rg + 3] * inv};
            f32x4 o1 = {accO1[4 * rg] * inv, accO1[4 * rg + 1] * inv,
                        accO1[4 * rg + 2] * inv, accO1[4 * rg + 3] * inv};
            *reinterpret_cast<f32x4*>(out + qrow * 64 + d0)      = o0;
            *reinterpret_cast<f32x4*>(out + qrow * 64 + 32 + d0) = o1;
        }
    } else {
        const int pb = batch * NCH + i;
        const int q = 32 * w + l31;
        unsigned short* ob = Opart + (size_t)pb * 8192 + q * 64;
        #pragma unroll
        for (int rg = 0; rg < 4; ++rg) {
            const int d0 = 4 * hi + 8 * rg;
            *reinterpret_cast<us4*>(ob + d0) =
                cvt4f(accO0[4 * rg], accO0[4 * rg + 1], accO0[4 * rg + 2], accO0[4 * rg + 3]);
            *reinterpret_cast<us4*>(ob + 32 + d0) =
                cvt4f(accO1[4 * rg], accO1[4 * rg + 1], accO1[4 * rg + 2], accO1[4 * rg + 3]);
        }
        if (hi == 0) lw[(size_t)pb * 128 + q] = l_run;
    }
}

// ---------------- K3: combine kv-split partials (qt >= 2): plain sums -------
__global__ __launch_bounds__(256) void k_combine(const unsigned short* __restrict__ Opart,
                                                 const float* __restrict__ lw,
                                                 float* __restrict__ out) {
    const int qt = 2 + (blockIdx.x >> 1), half = blockIdx.x & 1;
    const int batch = blockIdx.y;
    const int t = threadIdx.x;
    const int q = half * 64 + (t >> 2), d0 = (t & 3) * 16;
    const int ns = (qt + 2) >> 1;
    const int pb0 = batch * NCH + offf(qt);
    float num[16];
    #pragma unroll
    for (int j = 0; j < 16; ++j) num[j] = 0.f;
    float lsum = 0.f;
    for (int s = 0; s < ns; ++s) {
        const int pb = pb0 + s;
        lsum += lw[(size_t)pb * 128 + q];
        const unsigned short* op = Opart + (size_t)pb * 8192 + q * 64 + d0;
        us8 v0 = *reinterpret_cast<const us8*>(op);
        us8 v1 = *reinterpret_cast<const us8*>(op + 8);
        #pragma unroll
        for (int j = 0; j < 8; ++j) {
            num[j] += bf2f(v0[j]);
            num[8 + j] += bf2f(v1[j]);
        }
    }
    const float inv = 1.f / lsum;
    float* o = out + ((size_t)batch * T_SEQ + qt * 128 + q) * 64 + d0;
    #pragma unroll
    for (int h = 0; h < 4; ++h) {
        f32x4 v = {num[4 * h] * inv, num[4 * h + 1] * inv,
                   num[4 * h + 2] * inv, num[4 * h + 3] * inv};
        *reinterpret_cast<f32x4*>(o + 4 * h) = v;
    }
}

extern "C" void kernel_launch(void* const* d_in, const int* in_sizes, int n_in,
                              void* d_out, int out_size, void* d_ws, size_t ws_size,
                              hipStream_t stream) {
    (void)in_sizes; (void)n_in; (void)out_size; (void)ws_size;
    const float* x  = (const float*)d_in[0];
    const float* Wq = (const float*)d_in[1];
    const float* Wk = (const float*)d_in[2];
    const float* Wv = (const float*)d_in[3];
    float* out = (float*)d_out;
    unsigned short* ws16 = (unsigned short*)d_ws;
    unsigned short* wt_g  = ws16;                 // 16*192*64 = 196608 shorts
    unsigned short* qsb   = ws16 + 196608;        // 1048576
    unsigned short* ksb   = qsb + 1048576;
    unsigned short* vtb   = ksb + 1048576;        // 1048576
    unsigned short* Opart = vtb + 1048576;        // 4*272*8192 = 8912896 shorts
    float* lw = (float*)(Opart + 8912896);        // 4*272*128 f32
    k_wtrans <<<dim3(48),      dim3(256), 0, stream>>>(Wq, Wk, Wv, wt_g);
    k_proj   <<<dim3(512),     dim3(256), 0, stream>>>(x, wt_g, qsb, ksb, vtb);
    k_attn   <<<dim3(NCH, 4),  dim3(256), 0, stream>>>(qsb, ksb, vtb, Opart, lw, out);
    k_combine<<<dim3(60, 4),   dim3(256), 0, stream>>>(Opart, lw, out);
}

// Round 19
// 61.024 us; speedup vs baseline: 1.0575x; 1.0575x over previous
//
#include <hip/hip_runtime.h>

#define T_SEQ 4096
#define C_DIM 1024
#define HD 64
#define NCH 272           // chunks per batch: q-tile=128, chunk=4 kv-tiles

typedef __attribute__((ext_vector_type(8))) __bf16 bf16x8;
typedef __attribute__((ext_vector_type(8))) unsigned short us8;
typedef __attribute__((ext_vector_type(4))) unsigned short us4;
typedef __attribute__((ext_vector_type(4))) float f32x4;
typedef __attribute__((ext_vector_type(16))) float f32x16;

// 0.125 (1/sqrt(64)) * log2(e): fold softmax scale + base-2 conversion into q
#define QSCALE 0.18033688011112042f

__device__ __forceinline__ unsigned short f2bf(float f) {
    union { float f; unsigned u; } x; x.f = f;
    unsigned r = x.u + 0x7FFFu + ((x.u >> 16) & 1u);   // RNE
    return (unsigned short)(r >> 16);
}

__device__ __forceinline__ float bf2f(unsigned short u) {
    union { unsigned u; float f; } x; x.u = ((unsigned)u) << 16;
    return x.f;
}

__device__ __forceinline__ us8 cvt8(float4 a, float4 b) {
    union { __bf16 h[8]; us8 v; } u;
    u.h[0] = (__bf16)a.x; u.h[1] = (__bf16)a.y; u.h[2] = (__bf16)a.z; u.h[3] = (__bf16)a.w;
    u.h[4] = (__bf16)b.x; u.h[5] = (__bf16)b.y; u.h[6] = (__bf16)b.z; u.h[7] = (__bf16)b.w;
    return u.v;
}

__device__ __forceinline__ us4 cvt4f(float a, float b, float c, float d) {
    union { __bf16 h[4]; us4 v; } u;
    u.h[0] = (__bf16)a; u.h[1] = (__bf16)b; u.h[2] = (__bf16)c; u.h[3] = (__bf16)d;
    return u.v;
}

__device__ __forceinline__ f32x16 zero16() {
    f32x16 v;
    #pragma unroll
    for (int j = 0; j < 16; ++j) v[j] = 0.f;
    return v;
}

// XOR-swizzle on a short-index with 64-short (128 B) rows. Both write & read.
__device__ __forceinline__ int swzs(int idx) {
    return idx ^ ((((idx) >> 6) & 7) << 3);
}

// chunk-offset of q-tile qt (chunks of 4 kv-tiles; tile qt has 2qt+2 kv-tiles)
__device__ __forceinline__ int offf(int qt) {
    const int m = qt >> 1;
    return (qt & 1) ? (m + 1) * (m + 1) : m * m + m;
}

// ---------------- K0: W[1024][64] f32 -> wt2[16][192][64] bf16 --------------
// k-chunked layout: each K-step's W slice is a contiguous 24 KB block.
__global__ __launch_bounds__(256) void k_wtrans(const float* __restrict__ Wq,
                                                const float* __restrict__ Wk,
                                                const float* __restrict__ Wv,
                                                unsigned short* __restrict__ wt_g) {
    __shared__ unsigned short tile[64][72];
    const int bx = blockIdx.x;
    const int which = bx >> 4;          // 0..2
    const int kc = bx & 15;             // k-chunk
    const int k0 = kc * 64;
    const float* W = (which == 0) ? Wq : ((which == 1) ? Wk : Wv);
    const int t = threadIdx.x;
    {
        const int r = t >> 2, c0 = (t & 3) * 16;
        const float4* src = reinterpret_cast<const float4*>(W + (k0 + r) * HD + c0);
        #pragma unroll
        for (int i = 0; i < 4; ++i) {
            float4 v = src[i];
            tile[r][c0 + 4 * i + 0] = f2bf(v.x);
            tile[r][c0 + 4 * i + 1] = f2bf(v.y);
            tile[r][c0 + 4 * i + 2] = f2bf(v.z);
            tile[r][c0 + 4 * i + 3] = f2bf(v.w);
        }
    }
    __syncthreads();
    {
        const int n = t >> 2, kc0 = (t & 3) * 16;
        alignas(16) unsigned short o[16];
        #pragma unroll
        for (int i = 0; i < 16; ++i) o[i] = tile[kc0 + i][n];
        unsigned short* dst = wt_g + (size_t)kc * 12288 + (which * 64 + n) * 64 + kc0;
        *reinterpret_cast<us8*>(dst)     = *reinterpret_cast<const us8*>(&o[0]);
        *reinterpret_cast<us8*>(dst + 8) = *reinterpret_cast<const us8*>(&o[8]);
    }
}

// ---------------- K1: q,k,v projections, BM=32, W staged via LDS ------------
// (R12 best form.) Per K-step: cooperative COALESCED load of the 24 KB W
// chunk (6x16B/thread) + 32x64 x tile into dbuf LDS; 12 MFMA/wave; 1 barrier.
__global__ __launch_bounds__(256) void k_proj(const float* __restrict__ x,
                                              const unsigned short* __restrict__ wt_g,
                                              unsigned short* __restrict__ qs,
                                              unsigned short* __restrict__ ksb,
                                              unsigned short* __restrict__ vt) {
    // shorts: xs dbuf 2*2304 @0, W dbuf 2*13824 @4608 (64.5 KB -> 2 blocks/CU)
    __shared__ unsigned short smem[32256];
    const int tid = threadIdx.x;
    const int w = tid >> 6, lane = tid & 63;
    const int l15 = lane & 15, g = lane >> 4;
    const int m0 = blockIdx.x * 32;
    const int sr = tid >> 3, sc0 = (tid & 7) * 8;
    const float* xrow = x + (size_t)(m0 + sr) * C_DIM + sc0;

    f32x4 acc[3][2];
    #pragma unroll
    for (int mf = 0; mf < 3; ++mf)
        #pragma unroll
        for (int nf = 0; nf < 2; ++nf)
            acc[mf][nf] = (f32x4){0.f, 0.f, 0.f, 0.f};

    // prologue: stage step 0 into buf 0
    {
        float4 xa = *reinterpret_cast<const float4*>(xrow);
        float4 xb = *reinterpret_cast<const float4*>(xrow + 4);
        *reinterpret_cast<us8*>(smem + sr * 72 + sc0) = cvt8(xa, xb);
        #pragma unroll
        for (int j = 0; j < 6; ++j) {
            const int li = tid + 256 * j;
            us8 v = *reinterpret_cast<const us8*>(wt_g + li * 8);
            *reinterpret_cast<us8*>(smem + 4608 + (li >> 3) * 72 + (li & 7) * 8) = v;
        }
    }
    __syncthreads();

    for (int kk = 0; kk < 16; ++kk) {
        const int cur = kk & 1;
        const bool pf = (kk < 15);
        const int xb = cur * 2304;
        const int wb = 4608 + cur * 13824;
        const int xbn = (cur ^ 1) * 2304;
        const int wbn = 4608 + (cur ^ 1) * 13824;
        float4 na, nb;
        us8 wn[6];
        if (pf) {   // issue step kk+1 loads (coalesced; hidden under MFMA)
            na = *reinterpret_cast<const float4*>(xrow + (kk + 1) * 64);
            nb = *reinterpret_cast<const float4*>(xrow + (kk + 1) * 64 + 4);
            const unsigned short* wsrc = wt_g + (size_t)(kk + 1) * 12288;
            #pragma unroll
            for (int j = 0; j < 6; ++j)
                wn[j] = *reinterpret_cast<const us8*>(wsrc + (tid + 256 * j) * 8);
        }
        #pragma unroll
        for (int k2 = 0; k2 < 2; ++k2) {
            bf16x8 bfr[2];
            #pragma unroll
            for (int nf = 0; nf < 2; ++nf)
                bfr[nf] = *reinterpret_cast<const bf16x8*>(
                    smem + xb + (nf * 16 + l15) * 72 + k2 * 32 + g * 8);
            #pragma unroll
            for (int mf = 0; mf < 3; ++mf) {
                bf16x8 afr = *reinterpret_cast<const bf16x8*>(
                    smem + wb + ((3 * w + mf) * 16 + l15) * 72 + k2 * 32 + g * 8);
                #pragma unroll
                for (int nf = 0; nf < 2; ++nf)
                    acc[mf][nf] = __builtin_amdgcn_mfma_f32_16x16x32_bf16(
                        afr, bfr[nf], acc[mf][nf], 0, 0, 0);
            }
        }
        if (pf) {   // write step kk+1 into the other buffers
            *reinterpret_cast<us8*>(smem + xbn + sr * 72 + sc0) = cvt8(na, nb);
            #pragma unroll
            for (int j = 0; j < 6; ++j) {
                const int li = tid + 256 * j;
                *reinterpret_cast<us8*>(smem + wbn + (li >> 3) * 72 + (li & 7) * 8) = wn[j];
            }
        }
        __syncthreads();
    }

    // epilogue: C^T frags -> out_lds[32 m][208 n] bf16 (reuses smem)
    unsigned short* out_lds = smem;
    #pragma unroll
    for (int mf = 0; mf < 3; ++mf) {
        const int Mfr = 3 * w + mf;                    // n = 16*Mfr..
        const float s = (Mfr < 4) ? QSCALE : 1.0f;     // scale q columns (n<64)
        #pragma unroll
        for (int nf = 0; nf < 2; ++nf) {
            union { __bf16 h[4]; us4 v; } u;
            #pragma unroll
            for (int r = 0; r < 4; ++r) u.h[r] = (__bf16)(acc[mf][nf][r] * s);
            *reinterpret_cast<us4*>(out_lds + (nf * 16 + l15) * 208 + Mfr * 16 + 4 * g) = u.v;
        }
    }
    __syncthreads();
    {
        const int r = tid >> 3, c = (tid & 7) * 8;
        const size_t gm = (size_t)(m0 + r);
        *reinterpret_cast<us8*>(qs + gm * 64 + c)  = *reinterpret_cast<const us8*>(out_lds + r * 208 + c);
        *reinterpret_cast<us8*>(ksb + gm * 64 + c) = *reinterpret_cast<const us8*>(out_lds + r * 208 + 64 + c);
    }
    {
        const int d = tid >> 2, j0 = (tid & 3) * 8;
        const int b = m0 >> 12, t0 = m0 & 4095;
        alignas(16) unsigned short tmp[8];
        #pragma unroll
        for (int j = 0; j < 8; ++j) tmp[j] = out_lds[(j0 + j) * 208 + 128 + d];
        *reinterpret_cast<us8*>(vt + (size_t)(b * 64 + d) * T_SEQ + t0 + j0) =
            *reinterpret_cast<const us8*>(tmp);
    }
}

// ---------------- K2: flash attention, 32x32 MFMA, in-register P ------------
// (R12 best form.) grid (272, 4). Swapped QK^T with mfma_32x32x16; PV B-slot
// map k=4hi+(j&3)+8(j>>2) makes B-frags direct cvt of the S registers (no LDS
// P round-trip). V staged with matching column permutation. Fixed-base
// softmax (m=0); l accumulated in 4 independent partials.
__global__ __launch_bounds__(256) void k_attn(const unsigned short* __restrict__ qs,
                                              const unsigned short* __restrict__ ks,
                                              const unsigned short* __restrict__ vt,
                                              unsigned short* __restrict__ Opart,
                                              float* __restrict__ lw,
                                              float* __restrict__ out) {
    // shorts: kbuf[2][4096] @0, vbuf[2][4096] @8192  (32 KB total)
    __shared__ unsigned short sm[16384];
    const int tid = threadIdx.x;
    const int w = tid >> 6, lane = tid & 63;
    const int l31 = lane & 31, hi = lane >> 5;
    const int batch = blockIdx.y;
    const int i = (NCH - 1) - blockIdx.x;   // big q-tiles dispatched first
    // decode i -> (qt, split s)
    int qt = min(31, (int)(2.0f * sqrtf((float)i)));
    while (offf(qt + 1) <= i) ++qt;
    while (offf(qt) > i) --qt;
    const int s = i - offf(qt);
    const int ns = (qt + 2) >> 1;           // chunks for this q-tile
    const int it0 = s * 4;
    const int it1 = min(it0 + 4, 2 * qt + 2);
    const int qi = qt * 128 + 32 * w + l31;
    const size_t qrow = (size_t)batch * T_SEQ + qi;

    // Q B-frags: slot (hi,j) -> d = df*16 + hi*8 + j (same map as K A-frags)
    bf16x8 qf[4];
    #pragma unroll
    for (int df = 0; df < 4; ++df)
        qf[df] = *reinterpret_cast<const bf16x8*>(qs + qrow * 64 + df * 16 + hi * 8);

    f32x16 accO0 = zero16(), accO1 = zero16();
    float lp0 = 0.f, lp1 = 0.f, lp2 = 0.f, lp3 = 0.f;

    const int sr = tid >> 2, sc0 = (tid & 3) * 16;
    const unsigned short* kbase = ks + ((size_t)batch * T_SEQ + sr) * 64 + sc0;
    const unsigned short* vbase = vt + ((size_t)batch * 64 + sr) * T_SEQ + sc0;

    // V staging permutation: dest[0..15] = src[0..3, 8..11, 4..7, 12..15]
    // so a b128 read at hi*8 yields slots matching k = 4hi + (j&3) + 8*(j>>2).
    {
        us8 a0 = *reinterpret_cast<const us8*>(kbase + (size_t)it0 * 4096);
        us8 a1 = *reinterpret_cast<const us8*>(kbase + (size_t)it0 * 4096 + 8);
        us8 b0 = *reinterpret_cast<const us8*>(vbase + it0 * 64);
        us8 b1 = *reinterpret_cast<const us8*>(vbase + it0 * 64 + 8);
        us8 w0, w1;
        #pragma unroll
        for (int j = 0; j < 4; ++j) { w0[j] = b0[j]; w0[4 + j] = b1[j]; w1[j] = b0[4 + j]; w1[4 + j] = b1[4 + j]; }
        const int kd = sr * 64 + sc0, vd = 8192 + sr * 64 + sc0;
        *reinterpret_cast<us8*>(sm + swzs(kd))     = a0;
        *reinterpret_cast<us8*>(sm + swzs(kd + 8)) = a1;
        *reinterpret_cast<us8*>(sm + swzs(vd))     = w0;
        *reinterpret_cast<us8*>(sm + swzs(vd + 8)) = w1;
    }
    __syncthreads();

    for (int it = it0; it < it1; ++it) {
        const int cur = (it - it0) & 1;
        const bool pf = (it + 1 < it1);
        us8 n0, n1, m0, m1;
        if (pf) {   // issue next tile's loads early (hidden under compute)
            n0 = *reinterpret_cast<const us8*>(kbase + (size_t)(it + 1) * 4096);
            n1 = *reinterpret_cast<const us8*>(kbase + (size_t)(it + 1) * 4096 + 8);
            m0 = *reinterpret_cast<const us8*>(vbase + (it + 1) * 64);
            m1 = *reinterpret_cast<const us8*>(vbase + (it + 1) * 64 + 8);
        }
        const int kb = cur * 4096;
        const int vb = 8192 + cur * 4096;
        const bool diag = (it >= 2 * qt);

        #pragma unroll
        for (int ksub = 0; ksub < 2; ++ksub) {
            // QK^T: S^T[k 32][q 32] = K * Q^T over d=64 (4 mfma)
            f32x16 sv = zero16();
            __builtin_amdgcn_s_setprio(1);
            #pragma unroll
            for (int df = 0; df < 4; ++df) {
                bf16x8 afr = *reinterpret_cast<const bf16x8*>(
                    sm + swzs(kb + (ksub * 32 + l31) * 64 + df * 16 + hi * 8));
                sv = __builtin_amdgcn_mfma_f32_32x32x16_bf16(afr, qf[df], sv, 0, 0, 0);
            }
            __builtin_amdgcn_s_setprio(0);
            if (diag) {   // causal mask: k = it*64 + ksub*32 + (rr&3)+8*(rr>>2)+4*hi
                #pragma unroll
                for (int rr = 0; rr < 16; ++rr) {
                    const int kidx = it * 64 + ksub * 32 + (rr & 3) + 8 * (rr >> 2) + 4 * hi;
                    if (kidx > qi) sv[rr] = -1e30f;
                }
            }
            // P = exp2(S); l into 4 independent partials; pack to PV B-frags
            f32x16 pv;
            #pragma unroll
            for (int rr = 0; rr < 16; ++rr) pv[rr] = exp2f(sv[rr]);
            #pragma unroll
            for (int rr = 0; rr < 4; ++rr) {
                lp0 += pv[4 * rr + 0];
                lp1 += pv[4 * rr + 1];
                lp2 += pv[4 * rr + 2];
                lp3 += pv[4 * rr + 3];
            }
            us8 bfr0, bfr1;
            {
                us4 c0 = cvt4f(pv[0], pv[1], pv[2], pv[3]);
                us4 c1 = cvt4f(pv[4], pv[5], pv[6], pv[7]);
                us4 c2 = cvt4f(pv[8], pv[9], pv[10], pv[11]);
                us4 c3 = cvt4f(pv[12], pv[13], pv[14], pv[15]);
                #pragma unroll
                for (int j = 0; j < 4; ++j) {
                    bfr0[j] = c0[j]; bfr0[4 + j] = c1[j];
                    bfr1[j] = c2[j]; bfr1[4 + j] = c3[j];
                }
            }
            // PV: O^T[d 32][q 32] += V^T * P (2 d-tiles x 2 k-halves)
            __builtin_amdgcn_s_setprio(1);
            {
                bf16x8 a00 = *reinterpret_cast<const bf16x8*>(
                    sm + swzs(vb + l31 * 64 + ksub * 32 + hi * 8));
                bf16x8 a01 = *reinterpret_cast<const bf16x8*>(
                    sm + swzs(vb + l31 * 64 + ksub * 32 + 16 + hi * 8));
                accO0 = __builtin_amdgcn_mfma_f32_32x32x16_bf16(
                    a00, *reinterpret_cast<bf16x8*>(&bfr0), accO0, 0, 0, 0);
                accO0 = __builtin_amdgcn_mfma_f32_32x32x16_bf16(
                    a01, *reinterpret_cast<bf16x8*>(&bfr1), accO0, 0, 0, 0);
                bf16x8 a10 = *reinterpret_cast<const bf16x8*>(
                    sm + swzs(vb + (32 + l31) * 64 + ksub * 32 + hi * 8));
                bf16x8 a11 = *reinterpret_cast<const bf16x8*>(
                    sm + swzs(vb + (32 + l31) * 64 + ksub * 32 + 16 + hi * 8));
                accO1 = __builtin_amdgcn_mfma_f32_32x32x16_bf16(
                    a10, *reinterpret_cast<bf16x8*>(&bfr0), accO1, 0, 0, 0);
                accO1 = __builtin_amdgcn_mfma_f32_32x32x16_bf16(
                    a11, *reinterpret_cast<bf16x8*>(&bfr1), accO1, 0, 0, 0);
            }
            __builtin_amdgcn_s_setprio(0);
        }
        if (pf) {   // stage next tile into the other buffer (swizzled + V perm)
            us8 w0, w1;
            #pragma unroll
            for (int j = 0; j < 4; ++j) { w0[j] = m0[j]; w0[4 + j] = m1[j]; w1[j] = m0[4 + j]; w1[4 + j] = m1[4 + j]; }
            const int kd = (cur ^ 1) * 4096 + sr * 64 + sc0;
            const int vd = 8192 + (cur ^ 1) * 4096 + sr * 64 + sc0;
            *reinterpret_cast<us8*>(sm + swzs(kd))     = n0;
            *reinterpret_cast<us8*>(sm + swzs(kd + 8)) = n1;
            *reinterpret_cast<us8*>(sm + swzs(vd))     = w0;
            *reinterpret_cast<us8*>(sm + swzs(vd + 8)) = w1;
        }
        __syncthreads();
    }

    // merge partials + cross-half reduce (lane pair (l31,0)/(l31,1) = same q)
    float l_run = (lp0 + lp1) + (lp2 + lp3);
    l_run += __shfl_xor(l_run, 32, 64);

    if (ns == 1) {
        const float inv = 1.0f / l_run;
        #pragma unroll
        for (int rg = 0; rg < 4; ++rg) {
            const int d0 = 4 * hi + 8 * rg;
            f32x4 o0 = {accO0[4 * rg] * inv, accO0[4 * rg + 1] * inv,
                        accO0[4 * rg + 2] * inv, accO0[4 * rg + 3] * inv};
            f32x4 o1 = {accO1[4 * rg] * inv, accO1[4 * rg + 1] * inv,
                        accO1[4 * rg + 2] * inv, accO1[4 * rg + 3] * inv};
            *reinterpret_cast<f32x4*>(out + qrow * 64 + d0)      = o0;
            *reinterpret_cast<f32x4*>(out + qrow * 64 + 32 + d0) = o1;
        }
    } else {
        const int pb = batch * NCH + i;
        const int q = 32 * w + l31;
        unsigned short* ob = Opart + (size_t)pb * 8192 + q * 64;
        #pragma unroll
        for (int rg = 0; rg < 4; ++rg) {
            const int d0 = 4 * hi + 8 * rg;
            *reinterpret_cast<us4*>(ob + d0) =
                cvt4f(accO0[4 * rg], accO0[4 * rg + 1], accO0[4 * rg + 2], accO0[4 * rg + 3]);
            *reinterpret_cast<us4*>(ob + 32 + d0) =
                cvt4f(accO1[4 * rg], accO1[4 * rg + 1], accO1[4 * rg + 2], accO1[4 * rg + 3]);
        }
        if (hi == 0) lw[(size_t)pb * 128 + q] = l_run;
    }
}

// ---------------- K3: combine kv-split partials (qt >= 2): plain sums -------
__global__ __launch_bounds__(256) void k_combine(const unsigned short* __restrict__ Opart,
                                                 const float* __restrict__ lw,
                                                 float* __restrict__ out) {
    const int qt = 2 + (blockIdx.x >> 1), half = blockIdx.x & 1;
    const int batch = blockIdx.y;
    const int t = threadIdx.x;
    const int q = half * 64 + (t >> 2), d0 = (t & 3) * 16;
    const int ns = (qt + 2) >> 1;
    const int pb0 = batch * NCH + offf(qt);
    float num[16];
    #pragma unroll
    for (int j = 0; j < 16; ++j) num[j] = 0.f;
    float lsum = 0.f;
    for (int s = 0; s < ns; ++s) {
        const int pb = pb0 + s;
        lsum += lw[(size_t)pb * 128 + q];
        const unsigned short* op = Opart + (size_t)pb * 8192 + q * 64 + d0;
        us8 v0 = *reinterpret_cast<const us8*>(op);
        us8 v1 = *reinterpret_cast<const us8*>(op + 8);
        #pragma unroll
        for (int j = 0; j < 8; ++j) {
            num[j] += bf2f(v0[j]);
            num[8 + j] += bf2f(v1[j]);
        }
    }
    const float inv = 1.f / lsum;
    float* o = out + ((size_t)batch * T_SEQ + qt * 128 + q) * 64 + d0;
    #pragma unroll
    for (int h = 0; h < 4; ++h) {
        f32x4 v = {num[4 * h] * inv, num[4 * h + 1] * inv,
                   num[4 * h + 2] * inv, num[4 * h + 3] * inv};
        *reinterpret_cast<f32x4*>(o + 4 * h) = v;
    }
}

extern "C" void kernel_launch(void* const* d_in, const int* in_sizes, int n_in,
                              void* d_out, int out_size, void* d_ws, size_t ws_size,
                              hipStream_t stream) {
    (void)in_sizes; (void)n_in; (void)out_size; (void)ws_size;
    const float* x  = (const float*)d_in[0];
    const float* Wq = (const float*)d_in[1];
    const float* Wk = (const float*)d_in[2];
    const float* Wv = (const float*)d_in[3];
    float* out = (float*)d_out;
    unsigned short* ws16 = (unsigned short*)d_ws;
    unsigned short* wt_g  = ws16;                 // 16*192*64 = 196608 shorts
    unsigned short* qsb   = ws16 + 196608;        // 1048576
    unsigned short* ksb   = qsb + 1048576;
    unsigned short* vtb   = ksb + 1048576;        // 1048576
    unsigned short* Opart = vtb + 1048576;        // 4*272*8192 = 8912896 shorts
    float* lw = (float*)(Opart + 8912896);        // 4*272*128 f32
    k_wtrans <<<dim3(48),      dim3(256), 0, stream>>>(Wq, Wk, Wv, wt_g);
    k_proj   <<<dim3(512),     dim3(256), 0, stream>>>(x, wt_g, qsb, ksb, vtb);
    k_attn   <<<dim3(NCH, 4),  dim3(256), 0, stream>>>(qsb, ksb, vtb, Opart, lw, out);
    k_combine<<<dim3(60, 4),   dim3(256), 0, stream>>>(Opart, lw, out);
}